// Round 6
// baseline (231.138 us; speedup 1.0000x reference)
//
#include <hip/hip_runtime.h>

#define BB 64
#define CC 256
#define HW 3136            // 56*56
#define VEC4 (HW / 4)      // 784 float4 per plane = 12*64 + 16
#define NROW (BB * CC)     // 16384
#define NBLK (NROW / 4)    // 4096 blocks, 4 waves each, one wave per row

typedef float f32x4 __attribute__((ext_vector_type(4)));

// One 64-lane wave per (b,c) row. Copy x->out (NT store, cached load),
// accumulate per-row sum/sumsq. Last block computes BN + group stats.
__global__ __launch_bounds__(256) void fused_kernel(
    const float* __restrict__ x, float* __restrict__ out,
    float* __restrict__ s_ws, float* __restrict__ ss_ws,
    unsigned int* __restrict__ cnt) {
  const int row  = blockIdx.x * 4 + (threadIdx.x >> 6);
  const int lane = threadIdx.x & 63;
  const int t    = threadIdx.x;
  const size_t base = (size_t)row * HW;
  const f32x4* __restrict__ xv = (const f32x4*)(x + base);
  f32x4* __restrict__ ov = (f32x4*)(out + base);

  f32x4 v0, v1, v2, v3, v4, v5, v6, v7, v8, v9, v10, v11, vt;
  v0  = xv[lane +  0 * 64];
  v1  = xv[lane +  1 * 64];
  v2  = xv[lane +  2 * 64];
  v3  = xv[lane +  3 * 64];
  v4  = xv[lane +  4 * 64];
  v5  = xv[lane +  5 * 64];
  v6  = xv[lane +  6 * 64];
  v7  = xv[lane +  7 * 64];
  v8  = xv[lane +  8 * 64];
  v9  = xv[lane +  9 * 64];
  v10 = xv[lane + 10 * 64];
  v11 = xv[lane + 11 * 64];
  const bool tail = lane < 16;
  if (tail) vt = xv[768 + lane];

  float s = 0.f, ss = 0.f;
#define STEP(V, IDX)                                            \
  __builtin_nontemporal_store(V, &ov[IDX]);                     \
  s += V.x + V.y + V.z + V.w;                                   \
  ss += V.x * V.x + V.y * V.y + V.z * V.z + V.w * V.w;
  STEP(v0,  lane +  0 * 64)
  STEP(v1,  lane +  1 * 64)
  STEP(v2,  lane +  2 * 64)
  STEP(v3,  lane +  3 * 64)
  STEP(v4,  lane +  4 * 64)
  STEP(v5,  lane +  5 * 64)
  STEP(v6,  lane +  6 * 64)
  STEP(v7,  lane +  7 * 64)
  STEP(v8,  lane +  8 * 64)
  STEP(v9,  lane +  9 * 64)
  STEP(v10, lane + 10 * 64)
  STEP(v11, lane + 11 * 64)
  if (tail) {
    STEP(vt, 768 + lane)
  }
#undef STEP

  // wave64 down-reduce (no LDS, no barrier)
  for (int off = 32; off; off >>= 1) {
    s += __shfl_down(s, off, 64);
    ss += __shfl_down(ss, off, 64);
  }
  if (lane == 0) {
    s_ws[row]  = s;
    ss_ws[row] = ss;
  }

  // ---- elect last block ----
  __shared__ bool last;
  __syncthreads();                 // drains vmcnt: all 4 waves' stores issued
  if (t == 0) {
    __threadfence();               // publish s_ws/ss_ws device-wide
    last = (atomicAdd(cnt, 1u) == (unsigned)(NBLK - 1));
  }
  __syncthreads();
  if (!last) return;
  __threadfence();                 // acquire all blocks' writes

  // ---- stats tail (128 KB of s_ws/ss_ws, L2-hot) ----
  const size_t OX = (size_t)NROW * HW;
  float* mean_bn = out + OX;                 // [C]
  float* var_bn  = mean_bn + CC;             // [C]
  float* m2  = var_bn + CC;                  // [B,128]
  float* v2o = m2  + BB * 128;
  float* m4  = v2o + BB * 128;               // [B,64]
  float* v4o = m4  + BB * 64;
  float* m8  = v4o + BB * 64;                // [B,32]
  float* v8o = m8  + BB * 32;
  float* m16 = v8o + BB * 32;                // [B,16]
  float* v16 = m16 + BB * 16;

  // BatchNorm: t = channel
  {
    float S = 0.f, Q = 0.f;
#pragma unroll 8
    for (int bb = 0; bb < BB; ++bb) {
      S += s_ws[bb * CC + t];
      Q += ss_ws[bb * CC + t];
    }
    const float inv = 1.f / ((float)BB * (float)HW);
    const float m = S * inv;
    mean_bn[t] = m;
    var_bn[t]  = Q * inv - m * m;
  }

#define LEVEL(G, MP, VP)                                        \
  {                                                             \
    const int ng = CC / (G);                                    \
    const float inv = 1.f / ((float)(G) * (float)HW);           \
    for (int idx = t; idx < BB * ng; idx += 256) {              \
      const int bb = idx / ng;                                  \
      const int c  = idx - bb * ng;                             \
      const float* sp = s_ws  + bb * CC + c * (G);              \
      const float* qp = ss_ws + bb * CC + c * (G);              \
      float S = 0.f, Q = 0.f;                                   \
      _Pragma("unroll")                                         \
      for (int j = 0; j < (G); ++j) { S += sp[j]; Q += qp[j]; } \
      const float m = S * inv;                                  \
      (MP)[idx] = m;                                            \
      (VP)[idx] = Q * inv - m * m;                              \
    }                                                           \
  }
  LEVEL(2,  m2,  v2o)
  LEVEL(4,  m4,  v4o)
  LEVEL(8,  m8,  v8o)
  LEVEL(16, m16, v16)
#undef LEVEL
}

extern "C" void kernel_launch(void* const* d_in, const int* in_sizes, int n_in,
                              void* d_out, int out_size, void* d_ws, size_t ws_size,
                              hipStream_t stream) {
  const float* x = (const float*)d_in[0];
  float* out = (float*)d_out;
  float* s_ws = (float*)d_ws;                  // [B*C]
  float* ss_ws = s_ws + NROW;                  // [B*C]
  unsigned int* cnt = (unsigned int*)(ss_ws + NROW);

  hipMemsetAsync(cnt, 0, sizeof(unsigned int), stream);
  fused_kernel<<<NBLK, 256, 0, stream>>>(x, out, s_ws, ss_ws, cnt);
}

// Round 7
// 86.452 us; speedup vs baseline: 2.6736x; 2.6736x over previous
//
#include <hip/hip_runtime.h>

#define BB 64
#define CC 256
#define HW 3136            // 56*56
#define NROW (BB * CC)     // 16384
#define NBLK (NROW / 4)    // 4096 blocks, 4 waves each, one wave per row

typedef float f32x4 __attribute__((ext_vector_type(4)));

__device__ __forceinline__ float coh_load(const float* p) {
  return __hip_atomic_load(p, __ATOMIC_RELAXED, __HIP_MEMORY_SCOPE_AGENT);
}
__device__ __forceinline__ void coh_load2(const float* p, float& lo, float& hi) {
  unsigned long long u = __hip_atomic_load((const unsigned long long*)p,
                                           __ATOMIC_RELAXED, __HIP_MEMORY_SCOPE_AGENT);
  lo = __uint_as_float((unsigned)(u & 0xffffffffu));
  hi = __uint_as_float((unsigned)(u >> 32));
}

// One 64-lane wave per (b,c) row. Copy x->out (cached load, NT store),
// per-row sum/sumsq -> coherent (sc1) stores. Last block (atomic-counter
// election, NO fences) computes BN + hierarchical group stats.
__global__ __launch_bounds__(256) void fused_kernel(
    const float* __restrict__ x, float* __restrict__ out,
    float* __restrict__ ws, unsigned int* __restrict__ cnt) {
  float* s_ws   = ws;                 // [16384]
  float* ss_ws  = s_ws  + NROW;       // [16384]
  float* s2_ws  = ss_ws + NROW;       // [8192]
  float* ss2_ws = s2_ws + 8192;       // [8192]
  float* s4_ws  = ss2_ws + 8192;      // [4096]
  float* ss4_ws = s4_ws + 4096;       // [4096]
  float* s8_ws  = ss4_ws + 4096;      // [2048]
  float* ss8_ws = s8_ws + 2048;       // [2048]

  const int row  = blockIdx.x * 4 + (threadIdx.x >> 6);
  const int lane = threadIdx.x & 63;
  const int t    = threadIdx.x;
  const size_t base = (size_t)row * HW;
  const f32x4* __restrict__ xv = (const f32x4*)(x + base);
  f32x4* __restrict__ ov = (f32x4*)(out + base);

  f32x4 v0, v1, v2, v3, v4, v5, v6, v7, v8, v9, v10, v11, vt;
  v0  = xv[lane +  0 * 64];
  v1  = xv[lane +  1 * 64];
  v2  = xv[lane +  2 * 64];
  v3  = xv[lane +  3 * 64];
  v4  = xv[lane +  4 * 64];
  v5  = xv[lane +  5 * 64];
  v6  = xv[lane +  6 * 64];
  v7  = xv[lane +  7 * 64];
  v8  = xv[lane +  8 * 64];
  v9  = xv[lane +  9 * 64];
  v10 = xv[lane + 10 * 64];
  v11 = xv[lane + 11 * 64];
  const bool tail = lane < 16;
  if (tail) vt = xv[768 + lane];

  float s = 0.f, ss = 0.f;
#define STEP(V, IDX)                                            \
  __builtin_nontemporal_store(V, &ov[IDX]);                     \
  s += V.x + V.y + V.z + V.w;                                   \
  ss += V.x * V.x + V.y * V.y + V.z * V.z + V.w * V.w;
  STEP(v0,  lane +  0 * 64)
  STEP(v1,  lane +  1 * 64)
  STEP(v2,  lane +  2 * 64)
  STEP(v3,  lane +  3 * 64)
  STEP(v4,  lane +  4 * 64)
  STEP(v5,  lane +  5 * 64)
  STEP(v6,  lane +  6 * 64)
  STEP(v7,  lane +  7 * 64)
  STEP(v8,  lane +  8 * 64)
  STEP(v9,  lane +  9 * 64)
  STEP(v10, lane + 10 * 64)
  STEP(v11, lane + 11 * 64)
  if (tail) {
    STEP(vt, 768 + lane)
  }
#undef STEP

  for (int off = 32; off; off >>= 1) {
    s += __shfl_down(s, off, 64);
    ss += __shfl_down(ss, off, 64);
  }
  if (lane == 0) {
    // per-op coherent (sc1) stores: visible device-wide once vmcnt-complete,
    // no fence / L2 writeback needed.
    __hip_atomic_store(&s_ws[row],  s,  __ATOMIC_RELAXED, __HIP_MEMORY_SCOPE_AGENT);
    __hip_atomic_store(&ss_ws[row], ss, __ATOMIC_RELAXED, __HIP_MEMORY_SCOPE_AGENT);
  }

  // ---- elect last block (no fences) ----
  __shared__ bool last;
  __syncthreads();                 // drains each wave's vmcnt before barrier
  if (t == 0)
    last = (atomicAdd(cnt, 1u) == (unsigned)(NBLK - 1));
  __syncthreads();
  if (!last) return;

  // ---- stats tail, elected block only (reads via coherent loads) ----
  const size_t OX = (size_t)NROW * HW;
  float* mean_bn = out + OX;                 // [C]
  float* var_bn  = mean_bn + CC;             // [C]
  float* m2  = var_bn + CC;                  // [B,128]
  float* v2o = m2  + BB * 128;
  float* m4  = v2o + BB * 128;               // [B,64]
  float* v4o = m4  + BB * 64;
  float* m8  = v4o + BB * 64;                // [B,32]
  float* v8o = m8  + BB * 32;
  float* m16 = v8o + BB * 32;                // [B,16]
  float* v16 = m16 + BB * 16;

  // BatchNorm: t = channel, coalesced coherent loads
  {
    float S = 0.f, Q = 0.f;
#pragma unroll 8
    for (int bb = 0; bb < BB; ++bb) {
      S += coh_load(&s_ws[bb * CC + t]);
      Q += coh_load(&ss_ws[bb * CC + t]);
    }
    const float inv = 1.f / ((float)BB * (float)HW);
    const float m = S * inv;
    mean_bn[t] = m;
    var_bn[t]  = Q * inv - m * m;
  }

  // level 2: from s_ws (coherent 8B pair loads); stash sums for level 4
  {
    const float inv = 1.f / (2.f * HW);
#pragma unroll 4
    for (int i = t; i < BB * 128; i += 256) {
      const int bb = i >> 7, k = i & 127;
      float a, b2, c, d;
      coh_load2(&s_ws [bb * CC + 2 * k], a, b2);
      coh_load2(&ss_ws[bb * CC + 2 * k], c, d);
      const float S = a + b2, Q = c + d;
      s2_ws[i] = S; ss2_ws[i] = Q;
      const float m = S * inv;
      m2[i]  = m;
      v2o[i] = Q * inv - m * m;
    }
  }
  __syncthreads();   // s2 scratch visible block-wide (same CU L1)

  // level 4: from s2 scratch (plain cached loads; block-local data)
  {
    const float inv = 1.f / (4.f * HW);
#pragma unroll 4
    for (int i = t; i < BB * 64; i += 256) {
      const int bb = i >> 6, k = i & 63;
      const float S = s2_ws [bb * 128 + 2 * k] + s2_ws [bb * 128 + 2 * k + 1];
      const float Q = ss2_ws[bb * 128 + 2 * k] + ss2_ws[bb * 128 + 2 * k + 1];
      s4_ws[i] = S; ss4_ws[i] = Q;
      const float m = S * inv;
      m4[i]  = m;
      v4o[i] = Q * inv - m * m;
    }
  }
  __syncthreads();

  // level 8
  {
    const float inv = 1.f / (8.f * HW);
#pragma unroll 2
    for (int i = t; i < BB * 32; i += 256) {
      const int bb = i >> 5, k = i & 31;
      const float S = s4_ws [bb * 64 + 2 * k] + s4_ws [bb * 64 + 2 * k + 1];
      const float Q = ss4_ws[bb * 64 + 2 * k] + ss4_ws[bb * 64 + 2 * k + 1];
      s8_ws[i] = S; ss8_ws[i] = Q;
      const float m = S * inv;
      m8[i]  = m;
      v8o[i] = Q * inv - m * m;
    }
  }
  __syncthreads();

  // level 16
  {
    const float inv = 1.f / (16.f * HW);
    for (int i = t; i < BB * 16; i += 256) {
      const int bb = i >> 4, k = i & 15;
      const float S = s8_ws [bb * 32 + 2 * k] + s8_ws [bb * 32 + 2 * k + 1];
      const float Q = ss8_ws[bb * 32 + 2 * k] + ss8_ws[bb * 32 + 2 * k + 1];
      const float m = S * inv;
      m16[i] = m;
      v16[i] = Q * inv - m * m;
    }
  }
}

extern "C" void kernel_launch(void* const* d_in, const int* in_sizes, int n_in,
                              void* d_out, int out_size, void* d_ws, size_t ws_size,
                              hipStream_t stream) {
  const float* x = (const float*)d_in[0];
  float* out = (float*)d_out;
  float* ws = (float*)d_ws;
  // ws floats: 16384*2 + 8192*2 + 4096*2 + 2048*2 = 61440 (240 KB), cnt after
  unsigned int* cnt = (unsigned int*)(ws + 61440);

  hipMemsetAsync(cnt, 0, sizeof(unsigned int), stream);
  fused_kernel<<<NBLK, 256, 0, stream>>>(x, out, ws, cnt);
}

// Round 8
// 70.307 us; speedup vs baseline: 3.2875x; 1.2296x over previous
//
#include <hip/hip_runtime.h>

#define BB 64
#define CC 256
#define HW 3136            // 56*56
#define VEC (HW / 4)       // 784 float4 per (b,c) plane = 12*64 + 16
#define NROW (BB * CC)     // 16384

typedef float f32x4 __attribute__((ext_vector_type(4)));

// ---------------- Kernel 1: copy x -> out, per-(b,c) sum & sumsq ----------------
// One 64-lane wave per (b,c) row; 4 waves (4 rows) per block.
// A/B vs R4: plain cached stores instead of nontemporal stores.
__global__ __launch_bounds__(256) void reduce_copy_kernel(
    const float* __restrict__ x, float* __restrict__ out,
    float* __restrict__ s_ws, float* __restrict__ ss_ws) {
  const int row  = blockIdx.x * 4 + (threadIdx.x >> 6);
  const int lane = threadIdx.x & 63;
  const size_t base = (size_t)row * HW;
  const f32x4* __restrict__ xv = (const f32x4*)(x + base);
  f32x4* __restrict__ ov = (f32x4*)(out + base);

  f32x4 v0, v1, v2, v3, v4, v5, v6, v7, v8, v9, v10, v11, vt;
  v0  = __builtin_nontemporal_load(&xv[lane +  0 * 64]);
  v1  = __builtin_nontemporal_load(&xv[lane +  1 * 64]);
  v2  = __builtin_nontemporal_load(&xv[lane +  2 * 64]);
  v3  = __builtin_nontemporal_load(&xv[lane +  3 * 64]);
  v4  = __builtin_nontemporal_load(&xv[lane +  4 * 64]);
  v5  = __builtin_nontemporal_load(&xv[lane +  5 * 64]);
  v6  = __builtin_nontemporal_load(&xv[lane +  6 * 64]);
  v7  = __builtin_nontemporal_load(&xv[lane +  7 * 64]);
  v8  = __builtin_nontemporal_load(&xv[lane +  8 * 64]);
  v9  = __builtin_nontemporal_load(&xv[lane +  9 * 64]);
  v10 = __builtin_nontemporal_load(&xv[lane + 10 * 64]);
  v11 = __builtin_nontemporal_load(&xv[lane + 11 * 64]);
  const bool tail = lane < 16;
  if (tail) vt = __builtin_nontemporal_load(&xv[768 + lane]);

  float s = 0.f, ss = 0.f;
#define STEP(V, IDX)                                            \
  ov[IDX] = V;                                                  \
  s += V.x + V.y + V.z + V.w;                                   \
  ss += V.x * V.x + V.y * V.y + V.z * V.z + V.w * V.w;
  STEP(v0,  lane +  0 * 64)
  STEP(v1,  lane +  1 * 64)
  STEP(v2,  lane +  2 * 64)
  STEP(v3,  lane +  3 * 64)
  STEP(v4,  lane +  4 * 64)
  STEP(v5,  lane +  5 * 64)
  STEP(v6,  lane +  6 * 64)
  STEP(v7,  lane +  7 * 64)
  STEP(v8,  lane +  8 * 64)
  STEP(v9,  lane +  9 * 64)
  STEP(v10, lane + 10 * 64)
  STEP(v11, lane + 11 * 64)
  if (tail) {
    STEP(vt, 768 + lane)
  }
#undef STEP

  // wave64 down-reduce (no LDS, no barrier)
  for (int off = 32; off; off >>= 1) {
    s += __shfl_down(s, off, 64);
    ss += __shfl_down(ss, off, 64);
  }
  if (lane == 0) {
    s_ws[row]  = s;
    ss_ws[row] = ss;
  }
}

// ---------------- Kernel 2: BN stats + hierarchical group stats ----------------
__global__ __launch_bounds__(256) void stats_kernel(
    const float* __restrict__ s_ws, const float* __restrict__ ss_ws,
    float* __restrict__ out) {
  const size_t OX = (size_t)NROW * HW;      // x copy size
  float* mean_bn = out + OX;                // [C]
  float* var_bn  = mean_bn + CC;            // [C]
  float* m2  = var_bn + CC;                 // [B, C/2]
  float* v2  = m2 + BB * (CC / 2);
  float* m4  = v2 + BB * (CC / 2);          // [B, C/4]
  float* v4  = m4 + BB * (CC / 4);
  float* m8  = v4 + BB * (CC / 4);          // [B, C/8]
  float* v8  = m8 + BB * (CC / 8);
  float* m16 = v8 + BB * (CC / 8);          // [B, C/16]
  float* v16 = m16 + BB * (CC / 16);

  const int b = blockIdx.x;
  const int t = threadIdx.x;

  if (b == BB) {
    // BatchNorm stats: thread t = channel
    float S = 0.f, SS = 0.f;
    for (int bb = 0; bb < BB; ++bb) {
      S += s_ws[bb * CC + t];
      SS += ss_ws[bb * CC + t];
    }
    const float inv_n = 1.f / ((float)BB * (float)HW);
    const float m = S * inv_n;
    mean_bn[t] = m;
    var_bn[t]  = SS * inv_n - m * m;
    return;
  }

  __shared__ float ls2[128], lss2[128];
  __shared__ float ls4[64],  lss4[64];
  __shared__ float ls8[32],  lss8[32];

  if (t < 128) {
    float s2  = s_ws[b * CC + 2 * t] + s_ws[b * CC + 2 * t + 1];
    float ss2 = ss_ws[b * CC + 2 * t] + ss_ws[b * CC + 2 * t + 1];
    ls2[t] = s2; lss2[t] = ss2;
    const float inv_n = 1.f / (2.f * HW);
    const float m = s2 * inv_n;
    m2[b * 128 + t] = m;
    v2[b * 128 + t] = ss2 * inv_n - m * m;
  }
  __syncthreads();
  if (t < 64) {
    float s4  = ls2[2 * t] + ls2[2 * t + 1];
    float ss4 = lss2[2 * t] + lss2[2 * t + 1];
    ls4[t] = s4; lss4[t] = ss4;
    const float inv_n = 1.f / (4.f * HW);
    const float m = s4 * inv_n;
    m4[b * 64 + t] = m;
    v4[b * 64 + t] = ss4 * inv_n - m * m;
  }
  __syncthreads();
  if (t < 32) {
    float s8  = ls4[2 * t] + ls4[2 * t + 1];
    float ss8 = lss4[2 * t] + lss4[2 * t + 1];
    ls8[t] = s8; lss8[t] = ss8;
    const float inv_n = 1.f / (8.f * HW);
    const float m = s8 * inv_n;
    m8[b * 32 + t] = m;
    v8[b * 32 + t] = ss8 * inv_n - m * m;
  }
  __syncthreads();
  if (t < 16) {
    float s16  = ls8[2 * t] + ls8[2 * t + 1];
    float ss16 = lss8[2 * t] + lss8[2 * t + 1];
    const float inv_n = 1.f / (16.f * HW);
    const float m = s16 * inv_n;
    m16[b * 16 + t] = m;
    v16[b * 16 + t] = ss16 * inv_n - m * m;
  }
}

extern "C" void kernel_launch(void* const* d_in, const int* in_sizes, int n_in,
                              void* d_out, int out_size, void* d_ws, size_t ws_size,
                              hipStream_t stream) {
  const float* x = (const float*)d_in[0];
  float* out = (float*)d_out;
  float* s_ws = (float*)d_ws;          // [B*C]
  float* ss_ws = s_ws + NROW;          // [B*C]  (total 128 KB of d_ws)

  reduce_copy_kernel<<<NROW / 4, 256, 0, stream>>>(x, out, s_ws, ss_ws);
  stats_kernel<<<BB + 1, 256, 0, stream>>>(s_ws, ss_ws, out);
}